// Round 1
// 228.825 us; speedup vs baseline: 1.0138x; 1.0138x over previous
//
#include <hip/hip_runtime.h>

typedef float f32x4 __attribute__((ext_vector_type(4)));
typedef short short8 __attribute__((ext_vector_type(8)));
typedef short s16x4 __attribute__((ext_vector_type(4)));

#define MFMA16(a, b, c) __builtin_amdgcn_mfma_f32_16x16x32_bf16((a), (b), (c), 0, 0, 0)

#define T_ 256
#define B_ 1024
#define H_ 128
#define TB_ 262144
#define BH_ 131072
#define LOG2PI_F 1.8378770664093453f

__device__ inline short f2bf(float f) {
    unsigned u = __builtin_bit_cast(unsigned, f);
    u += 0x7fffu + ((u >> 16) & 1u);
    return (short)(u >> 16);
}
__device__ inline float bf2f(short s) {
    unsigned u = ((unsigned)(unsigned short)s) << 16;
    return __builtin_bit_cast(float, u);
}
__device__ inline float fexp(float x) { return __builtin_amdgcn_exp2f(x * 1.4426950408889634f); }
__device__ inline float fsigm(float x) { return __builtin_amdgcn_rcpf(1.f + fexp(-x)); }
__device__ inline float ftanh(float x) { return 1.f - 2.f * __builtin_amdgcn_rcpf(fexp(2.f * x) + 1.f); }

// ---------------- prep: weights f32 -> bf16, build packed head-weight ----------------
__global__ __launch_bounds__(256) void prep_kernel(
    const float* __restrict__ w1, const float* __restrict__ w2,
    const float* __restrict__ wih, const float* __restrict__ whh,
    const float* __restrict__ amw, const float* __restrict__ crw,
    short* __restrict__ w1b, short* __restrict__ w2b,
    short* __restrict__ wihb, short* __restrict__ whhb,
    short* __restrict__ headw)
{
    int i = blockIdx.x * blockDim.x + threadIdx.x;  // 65536 threads
    if (i < 16384) { w1b[i] = f2bf(w1[i]); w2b[i] = f2bf(w2[i]); }
    wihb[i] = f2bf(wih[i]);
    whhb[i] = f2bf(whh[i]);
    if (i < 2048) {
        int j = i >> 7, k = i & 127;
        float v = (j == 0) ? crw[k] : (j <= 8 ? amw[(j - 1) * 128 + k] : 0.f);
        headw[i] = f2bf(v);
    }
}

// ---------------- EX: encoder only (obs -> x2), 64-row tiles ----------------
// x2 layout: idx = ((t*256 + (b>>2))*4 + (b&3))*128 + dim   (1KB per (t, lstm-WG))
__global__ __launch_bounds__(512, 4) void ex_kernel(
    const float* __restrict__ obs, const float* __restrict__ eb1,
    const float* __restrict__ eb2,
    const short* __restrict__ w1b, const short* __restrict__ w2b,
    short* __restrict__ x2p)
{
    __shared__ __align__(16) short xtA[64 * 128];  // obs ping
    __shared__ __align__(16) short xtB[64 * 128];  // obs pong
    __shared__ __align__(16) short xtC[64 * 128];  // x1
    const int tid = threadIdx.x;
    const int l = tid & 63, w = tid >> 6;
    const int l15 = l & 15, kg = l >> 4;
    const int srow = tid >> 3, sln = tid & 7;      // staging: 8 threads/row
    const int ssw = (srow & 7) << 3;

    short8 fw1[4], fw2[4];
#pragma unroll
    for (int kk = 0; kk < 4; ++kk) {
        fw1[kk] = *(const short8*)&w1b[(w * 16 + l15) * 128 + kk * 32 + 8 * kg];
        fw2[kk] = *(const short8*)&w2b[(w * 16 + l15) * 128 + kk * 32 + 8 * kg];
        asm volatile("" : "+v"(fw1[kk]), "+v"(fw2[kk]));
    }
    const float bb1 = eb1[w * 16 + l15], bb2 = eb2[w * 16 + l15];

    const int NT = 8;  // 64-row tiles per block; 512 blocks x 8 = 4096 tiles
    const int t0 = blockIdx.x * NT;

    {
        const float* src = obs + ((size_t)t0 * 64 + srow) * 128 + sln * 16;
#pragma unroll
        for (int ii = 0; ii < 2; ++ii) {
            float4 v0 = *(const float4*)(src + ii * 8);
            float4 v1 = *(const float4*)(src + ii * 8 + 4);
            short8 p;
            p[0] = f2bf(v0.x); p[1] = f2bf(v0.y); p[2] = f2bf(v0.z); p[3] = f2bf(v0.w);
            p[4] = f2bf(v1.x); p[5] = f2bf(v1.y); p[6] = f2bf(v1.z); p[7] = f2bf(v1.w);
            *(short8*)(xtA + srow * 128 + ((sln * 16 + ii * 8) ^ ssw)) = p;
        }
    }
    __syncthreads();

    for (int i = 0; i < NT; ++i) {
        const int tile = t0 + i;
        short* bufO = (i & 1) ? xtB : xtA;
        short* bufN = (i & 1) ? xtA : xtB;

        float4 pf[4];
        {
            const int tn = (i + 1 < NT) ? tile + 1 : tile;
            const float* src = obs + ((size_t)tn * 64 + srow) * 128 + sln * 16;
#pragma unroll
            for (int ii = 0; ii < 4; ++ii) pf[ii] = *(const float4*)(src + ii * 4);
        }

        // G1: obs -> x1 (tanh)
#pragma unroll
        for (int mf = 0; mf < 4; ++mf) {
            const int ra = mf * 16 + l15, swa = (ra & 7) << 3;
            short8 a[4];
#pragma unroll
            for (int kk = 0; kk < 4; ++kk)
                a[kk] = *(const short8*)&bufO[ra * 128 + ((kk * 32 + 8 * kg) ^ swa)];
            f32x4 acc = {bb1, bb1, bb1, bb1};
#pragma unroll
            for (int kk = 0; kk < 4; ++kk) acc = MFMA16(a[kk], fw1[kk], acc);
#pragma unroll
            for (int j = 0; j < 4; ++j) {
                int rw = mf * 16 + kg * 4 + j;
                xtC[rw * 128 + ((w * 16 + l15) ^ ((rw & 7) << 3))] = f2bf(ftanh(acc[j]));
            }
        }
        __syncthreads();

        // G2: x1 -> x2 (tanh), direct global stores in lstm layout; also write obsN
        const int t = (tile * 64) >> 10;
        const int b_base = (tile * 64) & 1023;
#pragma unroll
        for (int mf = 0; mf < 4; ++mf) {
            const int ra = mf * 16 + l15, swa = (ra & 7) << 3;
            short8 a[4];
#pragma unroll
            for (int kk = 0; kk < 4; ++kk)
                a[kk] = *(const short8*)&xtC[ra * 128 + ((kk * 32 + 8 * kg) ^ swa)];
            f32x4 acc = {bb2, bb2, bb2, bb2};
#pragma unroll
            for (int kk = 0; kk < 4; ++kk) acc = MFMA16(a[kk], fw2[kk], acc);
#pragma unroll
            for (int j = 0; j < 4; ++j) {
                int b = b_base + mf * 16 + kg * 4 + j;
                size_t idx = (((size_t)t * 256 + (b >> 2)) * 4 + (b & 3)) * 128 + w * 16 + l15;
                x2p[idx] = f2bf(ftanh(acc[j]));
            }
        }
#pragma unroll
        for (int ii = 0; ii < 2; ++ii) {
            float4 v0 = pf[ii * 2], v1 = pf[ii * 2 + 1];
            short8 p;
            p[0] = f2bf(v0.x); p[1] = f2bf(v0.y); p[2] = f2bf(v0.z); p[3] = f2bf(v0.w);
            p[4] = f2bf(v1.x); p[5] = f2bf(v1.y); p[6] = f2bf(v1.z); p[7] = f2bf(v1.w);
            *(short8*)(bufN + srow * 128 + ((sln * 16 + ii * 8) ^ ssw)) = p;
        }
        __syncthreads();
    }
}

// ---------------- R: LSTM — x-gates fully register-resident (zero exchange) ----------------
// 4 rows/WG, 8 waves, 256 WGs. h-A rows ordered batch = row>>2 so ALL 4 C-regs of lane
// (kg,l15) hold batch kg -> no cndmask select (acc[s][0] directly). x2b is XOR-swizzled
// (col ^ ((row&7)<<3)) to kill the 8-way bank conflict on the x-chain ds_read_b128.
// Per step: 16 h-MFMA (M=4 used) + 4 x-MFMA (gate i_s of NEXT group, M=16 full, bh folded).
__global__ __launch_bounds__(512) void lstm_kernel(
    const short* __restrict__ x2p, const short* __restrict__ whhb,
    const short* __restrict__ wihb,
    const float* __restrict__ h0, const float* __restrict__ c0,
    const float* __restrict__ bhh, const float* __restrict__ bih,
    const float* __restrict__ dones,
    short* __restrict__ ys, float* __restrict__ out)
{
    __shared__ __align__(16) short hbuf[2][4 * 160];   // h dbuf, stride 160 (bank-clean)
    __shared__ __align__(16) short x2b[2][16 * 160];   // x2 group slots: [row=j*4+t_off][dim^swz]
    __shared__ float dlds[1028];                       // masks [t][j]
    const int tid = threadIdx.x;
    const int l = tid & 63, w = tid >> 6;
    const int l15 = l & 15, kg = l >> 4;
    const int b0 = blockIdx.x * 4;
    const int d = w * 16 + l15;
    const int blk = blockIdx.x;
    const int xsw = (l15 & 7) << 3;                    // x2b read-side XOR swizzle

    // persistent w_hh + w_ih B-frags (128 regs) + anti-remat pin
    short8 bfr[4][4], bfi[4][4];
#pragma unroll
    for (int s = 0; s < 4; ++s)
#pragma unroll
        for (int kk = 0; kk < 4; ++kk) {
            bfr[s][kk] = *(const short8*)&whhb[(s * 128 + d) * 128 + kk * 32 + 8 * kg];
            bfi[s][kk] = *(const short8*)&wihb[(s * 128 + d) * 128 + kk * 32 + 8 * kg];
            asm volatile("" : "+v"(bfr[s][kk]), "+v"(bfi[s][kk]));
        }

    for (int i = tid; i < 1028; i += 512) {
        int t = i >> 2, jj = i & 3;
        dlds[i] = (t < 256) ? 1.f - dones[t * 1024 + b0 + jj] : 1.f;
    }

    float bh[4];
#pragma unroll
    for (int s = 0; s < 4; ++s) bh[s] = bhh[s * 128 + d] + bih[s * 128 + d];

    // x2 staging: thread tid owns 8B: t_off=tid>>7, j=(tid>>5)&3, dim=(tid&31)*4
    // LDS row = j*4 + t_off  (batch-major, so MFMA reg j = t_off j for batch kg)
    const int st_toff = tid >> 7, st_j = (tid >> 5) & 3, st_dim = (tid & 31) * 4;
    const int st_row = st_j * 4 + st_toff;
    const int xrow160 = st_row * 160 + (st_dim ^ ((st_row & 7) << 3));  // swizzled write addr
#define X2GIDX(G) ((((size_t)(((G) * 4 + st_toff) <= 255 ? ((G) * 4 + st_toff) : 255) * 256 + blk) * 4 + st_j) * 128 + st_dim)

    // prologue: stage g0 -> x2b[0], g1 -> x2b[1]; issue g2 -> xpf
    {
        s16x4 v0 = *(const s16x4*)(x2p + X2GIDX(0));
        s16x4 v1 = *(const s16x4*)(x2p + X2GIDX(1));
        *(s16x4*)&x2b[0][xrow160] = v0;
        *(s16x4*)&x2b[1][xrow160] = v1;
    }
    s16x4 xpf = *(const s16x4*)(x2p + X2GIDX(2));
    asm volatile("s_waitcnt lgkmcnt(0)" ::: "memory");
    __syncthreads();

    // prologue x-chains for g0 (from x2b[0]) -> xgA, bh folded into init
    f32x4 xgA[4], xgB[4];
#pragma unroll
    for (int s = 0; s < 4; ++s) {
        short8 ax[4];
#pragma unroll
        for (int kk = 0; kk < 4; ++kk)
            ax[kk] = *(const short8*)&x2b[0][l15 * 160 + ((kk * 32 + kg * 8) ^ xsw)];
        f32x4 accX = {bh[s], bh[s], bh[s], bh[s]};
#pragma unroll
        for (int kk = 0; kk < 4; ++kk) accX = MFMA16(ax[kk], bfi[s][kk], accX);
        xgA[s] = accX;
    }

    float h = h0[(b0 + kg) * 128 + d];
    float c = c0[(b0 + kg) * 128 + d];
    hbuf[0][kg * 160 + d] = f2bf(h * dlds[kg]);
    asm volatile("s_waitcnt lgkmcnt(0)" ::: "memory");
    __syncthreads();

    const int aoff = (l15 >> 2) * 160;  // h-A rows: batch = row>>2 -> C reg j all batch kg
    float mreg = dlds[kg];

    // one LSTM step: consume xgC[s][i_s]; produce gate i_s of next group into xgN[i_s]
#define LSTM_STEP(t, hb, i_s, xgC, xgN, x2R, DO_T3, GNEXT)                                 \
    {                                                                                      \
        short8 a[4];                                                                       \
        _Pragma("unroll")                                                                  \
        for (int kk = 0; kk < 4; ++kk)                                                     \
            a[kk] = *(const short8*)&hbuf[hb][aoff + kk * 32 + kg * 8];                    \
        f32x4 acc[4];                                                                      \
        _Pragma("unroll")                                                                  \
        for (int s = 0; s < 4; ++s) acc[s] = f32x4{0.f, 0.f, 0.f, 0.f};                    \
        _Pragma("unroll")                                                                  \
        for (int kk = 0; kk < 4; ++kk)                                                     \
            _Pragma("unroll")                                                              \
            for (int s = 0; s < 4; ++s) acc[s] = MFMA16(a[kk], bfr[s][kk], acc[s]);        \
        { /* x-chain: gate i_s of next group, full M=16, bh folded */                      \
            short8 ax[4];                                                                  \
            _Pragma("unroll")                                                              \
            for (int kk = 0; kk < 4; ++kk)                                                 \
                ax[kk] = *(const short8*)&x2R[l15 * 160 + ((kk * 32 + kg * 8) ^ xsw)];     \
            const float bhx = bh[i_s];                                                     \
            f32x4 accX = {bhx, bhx, bhx, bhx};                                             \
            _Pragma("unroll")                                                              \
            for (int kk = 0; kk < 4; ++kk) accX = MFMA16(ax[kk], bfi[i_s][kk], accX);      \
            xgN[i_s] = accX;                                                               \
        }                                                                                  \
        if (DO_T3) {                                                                      \
            *(s16x4*)&x2W[xrow160] = xpf;                                                  \
            xpf = *(const s16x4*)(x2p + X2GIDX(GNEXT));                                    \
        }                                                                                  \
        float mn = dlds[((t) + 1) * 4 + kg];                                               \
        float gi = acc[0][0] + xgC[0][i_s];                                                \
        float gf = acc[1][0] + xgC[1][i_s];                                                \
        float gg = acc[2][0] + xgC[2][i_s];                                                \
        float go = acc[3][0] + xgC[3][i_s];                                                \
        c = fsigm(gf) * (c * mreg) + fsigm(gi) * ftanh(gg);                                \
        float h2 = fsigm(go) * ftanh(c);                                                   \
        h = h2;                                                                            \
        mreg = mn;                                                                         \
        hbuf[(hb) ^ 1][kg * 160 + d] = f2bf(h2 * mn);                                      \
        ys[((size_t)(t) * 1024 + b0 + kg) * 128 + d] = f2bf(h2);                           \
        asm volatile("s_waitcnt lgkmcnt(0)" ::: "memory");                                 \
        __builtin_amdgcn_s_barrier();                                                      \
        asm volatile("" ::: "memory");                                                     \
    }

    for (int g = 0; g < 64; g += 2) {
        {   // even group g: consume xgA, produce xgB from x2b[1] (group g+1)
            const int tb = g * 4;
            const short* x2R = &x2b[1][0];
            short* x2W = &x2b[0][0];   // at t3: stage group g+2 into slot 0
            LSTM_STEP(tb + 0, 0, 0, xgA, xgB, x2R, 0, 0);
            LSTM_STEP(tb + 1, 1, 1, xgA, xgB, x2R, 0, 0);
            LSTM_STEP(tb + 2, 0, 2, xgA, xgB, x2R, 0, 0);
            LSTM_STEP(tb + 3, 1, 3, xgA, xgB, x2R, 1, (g + 3));
        }
        {   // odd group g+1: consume xgB, produce xgA from x2b[0] (group g+2)
            const int tb = (g + 1) * 4;
            const short* x2R = &x2b[0][0];
            short* x2W = &x2b[1][0];   // at t3: stage group g+3 into slot 1
            LSTM_STEP(tb + 0, 0, 0, xgB, xgA, x2R, 0, 0);
            LSTM_STEP(tb + 1, 1, 1, xgB, xgA, x2R, 0, 0);
            LSTM_STEP(tb + 2, 0, 2, xgB, xgA, x2R, 0, 0);
            LSTM_STEP(tb + 3, 1, 3, xgB, xgA, x2R, 1, (g + 4));
        }
    }
#undef LSTM_STEP
#undef X2GIDX

    out[3 * TB_ + (b0 + kg) * 128 + d] = h;
    out[3 * TB_ + BH_ + (b0 + kg) * 128 + d] = c;
}

// ---------------- H: heads — direct-from-global A-frags, no barrier, full-lane logprob ----------------
__global__ __launch_bounds__(256) void head_kernel(
    const short* __restrict__ ys, const short* __restrict__ headw,
    const float* __restrict__ crb, const float* __restrict__ amb,
    const float* __restrict__ lstd, const float* __restrict__ actions,
    float* __restrict__ out)
{
    __shared__ float heads[256][12];
    const int tid = threadIdx.x;
    const int l = tid & 63, w = tid >> 6;
    const int l15 = l & 15, kg = l >> 4;
    const int rr0 = blockIdx.x * 256;
    const int rw0 = rr0 + w * 64;

    short8 bb[4];
#pragma unroll
    for (int kk = 0; kk < 4; ++kk)
        bb[kk] = *(const short8*)&headw[l15 * 128 + kk * 32 + 8 * kg];
    const float bias = (l15 == 0) ? crb[0] : (l15 <= 8 ? amb[l15 - 1] : 0.f);

#pragma unroll
    for (int rt = 0; rt < 4; ++rt) {
        const short* src = ys + (size_t)(rw0 + rt * 16 + l15) * 128;
        short8 a[4];
#pragma unroll
        for (int kk = 0; kk < 4; ++kk)
            a[kk] = *(const short8*)(src + kk * 32 + 8 * kg);
        f32x4 acc = {bias, bias, bias, bias};
#pragma unroll
        for (int kk = 0; kk < 4; ++kk) acc = MFMA16(a[kk], bb[kk], acc);
        if (l15 < 9) {
#pragma unroll
            for (int j = 0; j < 4; ++j)
                heads[w * 64 + rt * 16 + kg * 4 + j][l15] = acc[j];
        }
    }
    asm volatile("s_waitcnt lgkmcnt(0)" ::: "memory");

    const int r = rw0 + l;
    const float* hp = heads[w * 64 + l];
    const float* ap = actions + (size_t)r * 8;
    float4 a0 = *(const float4*)(ap);
    float4 a1 = *(const float4*)(ap + 4);
    float lp = 0.f, lj = 0.f, entS = 0.f;
#pragma unroll
    for (int ai = 0; ai < 8; ++ai) {
        float x = (ai < 4) ? ((ai == 0) ? a0.x : (ai == 1) ? a0.y : (ai == 2) ? a0.z : a0.w)
                           : ((ai == 4) ? a1.x : (ai == 5) ? a1.y : (ai == 6) ? a1.z : a1.w);
        float xc = fminf(fmaxf(x, -1.f + 1e-6f), 1.f - 1e-6f);
        float u = 0.5f * logf((1.f + xc) / (1.f - xc));
        float ls = lstd[ai];
        float z = (u - hp[1 + ai]) * expf(-ls);
        lp += -0.5f * z * z - ls;
        lj += logf(1.f - x * x + 1e-6f);
        entS += ls;
    }
    lp -= 8.f * 0.5f * LOG2PI_F;
    entS += 8.f * (0.5f + 0.5f * LOG2PI_F);
    out[r] = lp - lj;
    out[TB_ + r] = entS + lj;
    out[2 * TB_ + r] = hp[0];
}

extern "C" void kernel_launch(void* const* d_in, const int* in_sizes, int n_in,
                              void* d_out, int out_size, void* d_ws, size_t ws_size,
                              hipStream_t stream) {
    const float* obs   = (const float*)d_in[0];
    const float* acts  = (const float*)d_in[1];
    const float* dones = (const float*)d_in[2];
    const float* h0    = (const float*)d_in[3];
    const float* c0    = (const float*)d_in[4];
    const float* w1    = (const float*)d_in[5];
    const float* b1    = (const float*)d_in[6];
    const float* w2    = (const float*)d_in[7];
    const float* b2    = (const float*)d_in[8];
    const float* wih   = (const float*)d_in[9];
    const float* whh   = (const float*)d_in[10];
    const float* bih   = (const float*)d_in[11];
    const float* bhh   = (const float*)d_in[12];
    const float* amw   = (const float*)d_in[13];
    const float* amb   = (const float*)d_in[14];
    const float* lstd  = (const float*)d_in[15];
    const float* crw   = (const float*)d_in[16];
    const float* crb   = (const float*)d_in[17];
    float* out = (float*)d_out;

    char* ws = (char*)d_ws;
    short* w1b   = (short*)(ws + 0);        // 32 KB
    short* w2b   = (short*)(ws + 32768);    // 32 KB
    short* wihb  = (short*)(ws + 65536);    // 128 KB
    short* whhb  = (short*)(ws + 196608);   // 128 KB
    short* headw = (short*)(ws + 327680);   // 4 KB
    short* x2p   = (short*)(ws + 524288);   // 64 MB  [t][blk][j][dim] bf16
    short* ysb   = (short*)(ws + 524288 + 67108864);  // 64 MB [t*1024+b][128] bf16
    if (ws_size < (size_t)524288 + 67108864 + 67108864) return;

    hipLaunchKernelGGL(prep_kernel, dim3(256), dim3(256), 0, stream,
                       w1, w2, wih, whh, amw, crw, w1b, w2b, wihb, whhb, headw);
    hipLaunchKernelGGL(ex_kernel, dim3(512), dim3(512), 0, stream,
                       obs, b1, b2, w1b, w2b, x2p);
    hipLaunchKernelGGL(lstm_kernel, dim3(256), dim3(512), 0, stream,
                       x2p, whhb, wihb, h0, c0, bhh, bih, dones, ysb, out);
    hipLaunchKernelGGL(head_kernel, dim3(1024), dim3(256), 0, stream,
                       ysb, headw, crb, amb, lstd, acts, out);
}

// Round 3
// 216.154 us; speedup vs baseline: 1.0733x; 1.0586x over previous
//
#include <hip/hip_runtime.h>

typedef float f32x4 __attribute__((ext_vector_type(4)));
typedef short short8 __attribute__((ext_vector_type(8)));
typedef short s16x4 __attribute__((ext_vector_type(4)));

#define MFMA16(a, b, c) __builtin_amdgcn_mfma_f32_16x16x32_bf16((a), (b), (c), 0, 0, 0)

#define T_ 256
#define B_ 1024
#define H_ 128
#define TB_ 262144
#define BH_ 131072
#define LOG2PI_F 1.8378770664093453f

__device__ inline short f2bf(float f) {
    unsigned u = __builtin_bit_cast(unsigned, f);
    u += 0x7fffu + ((u >> 16) & 1u);
    return (short)(u >> 16);
}
__device__ inline float fexp(float x) { return __builtin_amdgcn_exp2f(x * 1.4426950408889634f); }
__device__ inline float fsigm(float x) { return __builtin_amdgcn_rcpf(1.f + fexp(-x)); }
__device__ inline float ftanh(float x) { return 1.f - 2.f * __builtin_amdgcn_rcpf(fexp(2.f * x) + 1.f); }

__device__ inline short8 pack8(float4 u0, float4 u1) {
    short8 p;
    p[0] = f2bf(u0.x); p[1] = f2bf(u0.y); p[2] = f2bf(u0.z); p[3] = f2bf(u0.w);
    p[4] = f2bf(u1.x); p[5] = f2bf(u1.y); p[6] = f2bf(u1.z); p[7] = f2bf(u1.w);
    return p;
}

// ---------------- EX: encoder only (obs -> x2), 64-row tiles; weights converted in-reg ----------------
// x2 layout: idx = ((t*256 + (b>>2))*4 + (b&3))*128 + dim   (1KB per (t, lstm-WG))
__global__ __launch_bounds__(512, 4) void ex_kernel(
    const float* __restrict__ obs, const float* __restrict__ eb1,
    const float* __restrict__ eb2,
    const float* __restrict__ w1f, const float* __restrict__ w2f,
    short* __restrict__ x2p)
{
    __shared__ __align__(16) short xtA[64 * 128];  // obs ping
    __shared__ __align__(16) short xtB[64 * 128];  // obs pong
    __shared__ __align__(16) short xtC[64 * 128];  // x1
    const int tid = threadIdx.x;
    const int l = tid & 63, w = tid >> 6;
    const int l15 = l & 15, kg = l >> 4;
    const int srow = tid >> 3, sln = tid & 7;      // staging: 8 threads/row
    const int ssw = (srow & 7) << 3;

    short8 fw1[4], fw2[4];
#pragma unroll
    for (int kk = 0; kk < 4; ++kk) {
        const float* s1 = w1f + (w * 16 + l15) * 128 + kk * 32 + 8 * kg;
        const float* s2 = w2f + (w * 16 + l15) * 128 + kk * 32 + 8 * kg;
        fw1[kk] = pack8(*(const float4*)s1, *(const float4*)(s1 + 4));
        fw2[kk] = pack8(*(const float4*)s2, *(const float4*)(s2 + 4));
        asm volatile("" : "+v"(fw1[kk]), "+v"(fw2[kk]));
    }
    const float bb1 = eb1[w * 16 + l15], bb2 = eb2[w * 16 + l15];

    const int NT = 8;  // 64-row tiles per block; 512 blocks x 8 = 4096 tiles
    const int t0 = blockIdx.x * NT;

    {
        const float* src = obs + ((size_t)t0 * 64 + srow) * 128 + sln * 16;
#pragma unroll
        for (int ii = 0; ii < 2; ++ii) {
            float4 v0 = *(const float4*)(src + ii * 8);
            float4 v1 = *(const float4*)(src + ii * 8 + 4);
            *(short8*)(xtA + srow * 128 + ((sln * 16 + ii * 8) ^ ssw)) = pack8(v0, v1);
        }
    }
    __syncthreads();

    for (int i = 0; i < NT; ++i) {
        const int tile = t0 + i;
        short* bufO = (i & 1) ? xtB : xtA;
        short* bufN = (i & 1) ? xtA : xtB;

        float4 pf[4];
        {
            const int tn = (i + 1 < NT) ? tile + 1 : tile;
            const float* src = obs + ((size_t)tn * 64 + srow) * 128 + sln * 16;
#pragma unroll
            for (int ii = 0; ii < 4; ++ii) pf[ii] = *(const float4*)(src + ii * 4);
        }

        // G1: obs -> x1 (tanh)
#pragma unroll
        for (int mf = 0; mf < 4; ++mf) {
            const int ra = mf * 16 + l15, swa = (ra & 7) << 3;
            short8 a[4];
#pragma unroll
            for (int kk = 0; kk < 4; ++kk)
                a[kk] = *(const short8*)&bufO[ra * 128 + ((kk * 32 + 8 * kg) ^ swa)];
            f32x4 acc = {bb1, bb1, bb1, bb1};
#pragma unroll
            for (int kk = 0; kk < 4; ++kk) acc = MFMA16(a[kk], fw1[kk], acc);
#pragma unroll
            for (int j = 0; j < 4; ++j) {
                int rw = mf * 16 + kg * 4 + j;
                xtC[rw * 128 + ((w * 16 + l15) ^ ((rw & 7) << 3))] = f2bf(ftanh(acc[j]));
            }
        }
        __syncthreads();

        // G2: x1 -> x2 (tanh), direct global stores in lstm layout; also write obsN
        const int t = (tile * 64) >> 10;
        const int b_base = (tile * 64) & 1023;
#pragma unroll
        for (int mf = 0; mf < 4; ++mf) {
            const int ra = mf * 16 + l15, swa = (ra & 7) << 3;
            short8 a[4];
#pragma unroll
            for (int kk = 0; kk < 4; ++kk)
                a[kk] = *(const short8*)&xtC[ra * 128 + ((kk * 32 + 8 * kg) ^ swa)];
            f32x4 acc = {bb2, bb2, bb2, bb2};
#pragma unroll
            for (int kk = 0; kk < 4; ++kk) acc = MFMA16(a[kk], fw2[kk], acc);
#pragma unroll
            for (int j = 0; j < 4; ++j) {
                int b = b_base + mf * 16 + kg * 4 + j;
                size_t idx = (((size_t)t * 256 + (b >> 2)) * 4 + (b & 3)) * 128 + w * 16 + l15;
                x2p[idx] = f2bf(ftanh(acc[j]));
            }
        }
#pragma unroll
        for (int ii = 0; ii < 2; ++ii) {
            *(short8*)(bufN + srow * 128 + ((sln * 16 + ii * 8) ^ ssw)) =
                pack8(pf[ii * 2], pf[ii * 2 + 1]);
        }
        __syncthreads();
    }
}

// ---------------- R: LSTM + fused heads ----------------
// 4 rows/WG, 8 waves, 256 WGs. h-A rows quad-replicated (batch = row>>2) so all 4 C-regs
// of lane (kg,l15) hold batch kg. xg kept in f32 regs; xgC[s] fed as MFMA C-in (C-in fusion:
// no acc zero-init, no add). Unmasked h2 kept in a 16-slot LDS ring; every 8th step all 8
// waves each compute one past timestep's 9-dim head (value+mean) and store f32 to headbuf.
__global__ __launch_bounds__(512) void lstm_kernel(
    const short* __restrict__ x2p, const float* __restrict__ whh,
    const float* __restrict__ wih,
    const float* __restrict__ h0, const float* __restrict__ c0,
    const float* __restrict__ bhh, const float* __restrict__ bih,
    const float* __restrict__ dones,
    const float* __restrict__ amw, const float* __restrict__ crw,
    const float* __restrict__ amb, const float* __restrict__ crb,
    float* __restrict__ headbuf, float* __restrict__ out)
{
    __shared__ __align__(16) short hbuf[2][4 * 160];   // masked h dbuf (MFMA A source)
    __shared__ __align__(16) short hring[16 * 640];    // unmasked h2 ring [slot][4*160]
    __shared__ __align__(16) short x2b[2][16 * 160];   // x2 group slots (XOR-swizzled)
    __shared__ float dlds[1028];                       // masks [t][j]
    const int tid = threadIdx.x;
    const int l = tid & 63, w = tid >> 6;
    const int l15 = l & 15, kg = l >> 4;
    const int b0 = blockIdx.x * 4;
    const int d = w * 16 + l15;
    const int blk = blockIdx.x;
    const int xsw = (l15 & 7) << 3;                    // x2b read-side XOR swizzle

    // persistent w_hh + w_ih B-frags, converted in-reg from f32 (+ anti-remat pin)
    short8 bfr[4][4], bfi[4][4];
#pragma unroll
    for (int s = 0; s < 4; ++s)
#pragma unroll
        for (int kk = 0; kk < 4; ++kk) {
            const float* sr = whh + ((s * 128 + d) * 128 + kk * 32 + 8 * kg);
            const float* si = wih + ((s * 128 + d) * 128 + kk * 32 + 8 * kg);
            bfr[s][kk] = pack8(*(const float4*)sr, *(const float4*)(sr + 4));
            bfi[s][kk] = pack8(*(const float4*)si, *(const float4*)(si + 4));
            asm volatile("" : "+v"(bfr[s][kk]), "+v"(bfi[s][kk]));
        }

    // head B-frags: row l15: 0 = cr_w, 1..8 = am_w[l15-1], 9..15 = 0
    short8 hb4[4];
#pragma unroll
    for (int kk = 0; kk < 4; ++kk) {
        if (l15 == 0) {
            const float* s0 = crw + kk * 32 + 8 * kg;
            hb4[kk] = pack8(*(const float4*)s0, *(const float4*)(s0 + 4));
        } else if (l15 <= 8) {
            const float* s0 = amw + (l15 - 1) * 128 + kk * 32 + 8 * kg;
            hb4[kk] = pack8(*(const float4*)s0, *(const float4*)(s0 + 4));
        } else {
            hb4[kk] = short8{0, 0, 0, 0, 0, 0, 0, 0};
        }
        asm volatile("" : "+v"(hb4[kk]));
    }
    const float biasH = (l15 == 0) ? crb[0] : (l15 <= 8 ? amb[l15 - 1] : 0.f);

    for (int i = tid; i < 1028; i += 512) {
        int t = i >> 2, jj = i & 3;
        dlds[i] = (t < 256) ? 1.f - dones[t * 1024 + b0 + jj] : 1.f;
    }

    float bh[4];
#pragma unroll
    for (int s = 0; s < 4; ++s) bh[s] = bhh[s * 128 + d] + bih[s * 128 + d];

    // x2 staging: thread tid owns 8B: t_off=tid>>7, j=(tid>>5)&3, dim=(tid&31)*4
    const int st_toff = tid >> 7, st_j = (tid >> 5) & 3, st_dim = (tid & 31) * 4;
    const int st_row = st_j * 4 + st_toff;
    const int xrow160 = st_row * 160 + (st_dim ^ ((st_row & 7) << 3));  // swizzled write addr
#define X2GIDX(G) ((((size_t)(((G) * 4 + st_toff) <= 255 ? ((G) * 4 + st_toff) : 255) * 256 + blk) * 4 + st_j) * 128 + st_dim)

    // prologue: stage g0 -> x2b[0], g1 -> x2b[1]; issue g2 -> xpf
    {
        s16x4 v0 = *(const s16x4*)(x2p + X2GIDX(0));
        s16x4 v1 = *(const s16x4*)(x2p + X2GIDX(1));
        *(s16x4*)&x2b[0][xrow160] = v0;
        *(s16x4*)&x2b[1][xrow160] = v1;
    }
    s16x4 xpf = *(const s16x4*)(x2p + X2GIDX(2));
    asm volatile("s_waitcnt lgkmcnt(0)" ::: "memory");
    __syncthreads();

    // prologue x-chains for g0 (from x2b[0]) -> xgA, bh folded into C-init
    f32x4 xgA[4], xgB[4];
#pragma unroll
    for (int s = 0; s < 4; ++s) {
        short8 ax[4];
#pragma unroll
        for (int kk = 0; kk < 4; ++kk)
            ax[kk] = *(const short8*)&x2b[0][l15 * 160 + ((kk * 32 + kg * 8) ^ xsw)];
        f32x4 accX = {bh[s], bh[s], bh[s], bh[s]};
#pragma unroll
        for (int kk = 0; kk < 4; ++kk) accX = MFMA16(ax[kk], bfi[s][kk], accX);
        xgA[s] = accX;
    }

    float h = h0[(b0 + kg) * 128 + d];
    float c = c0[(b0 + kg) * 128 + d];
    hbuf[0][kg * 160 + d] = f2bf(h * dlds[kg]);
    asm volatile("s_waitcnt lgkmcnt(0)" ::: "memory");
    __syncthreads();

    const int aoff = (l15 >> 2) * 160;  // quad-replicated A rows: batch = row>>2
    float mreg = dlds[kg];

    // one LSTM step; DO_HEAD: all 8 waves each do one past step's head (t-8+w) from the ring
#define LSTM_STEP(t, hb, i_s, xgC, xgN, x2R, DO_T3, GNEXT, DO_HEAD)                        \
    {                                                                                      \
        short8 a[4];                                                                       \
        _Pragma("unroll")                                                                  \
        for (int kk = 0; kk < 4; ++kk)                                                     \
            a[kk] = *(const short8*)&hbuf[hb][aoff + kk * 32 + kg * 8];                    \
        f32x4 acc[4];                                                                      \
        _Pragma("unroll")                                                                  \
        for (int s = 0; s < 4; ++s) acc[s] = xgC[s];                                       \
        _Pragma("unroll")                                                                  \
        for (int kk = 0; kk < 4; ++kk)                                                     \
            _Pragma("unroll")                                                              \
            for (int s = 0; s < 4; ++s) acc[s] = MFMA16(a[kk], bfr[s][kk], acc[s]);        \
        { /* x-chain: gate i_s of next group, full M=16, bh folded into C-init */          \
            short8 ax[4];                                                                  \
            _Pragma("unroll")                                                              \
            for (int kk = 0; kk < 4; ++kk)                                                 \
                ax[kk] = *(const short8*)&x2R[l15 * 160 + ((kk * 32 + kg * 8) ^ xsw)];     \
            f32x4 accX = {bh[i_s], bh[i_s], bh[i_s], bh[i_s]};                             \
            _Pragma("unroll")                                                              \
            for (int kk = 0; kk < 4; ++kk) accX = MFMA16(ax[kk], bfi[i_s][kk], accX);      \
            xgN[i_s] = accX;                                                               \
        }                                                                                  \
        if (DO_HEAD) { /* head for step th = t-8+w, from ring slot th&15 */                \
            int th = (t) - 8 + w;                                                          \
            const short* hr = &hring[(th & 15) * 640];                                     \
            short8 ah[4];                                                                  \
            _Pragma("unroll")                                                              \
            for (int kk = 0; kk < 4; ++kk)                                                 \
                ah[kk] = *(const short8*)&hr[aoff + kk * 32 + kg * 8];                     \
            f32x4 aH = {biasH, biasH, biasH, biasH};                                       \
            _Pragma("unroll")                                                              \
            for (int kk = 0; kk < 4; ++kk) aH = MFMA16(ah[kk], hb4[kk], aH);               \
            if (l15 < 9) headbuf[(th * 1024 + b0 + kg) * 12 + l15] = aH[0];                \
        }                                                                                  \
        if (DO_T3) {                                                                      \
            *(s16x4*)&x2W[xrow160] = xpf;                                                  \
            xpf = *(const s16x4*)(x2p + X2GIDX(GNEXT));                                    \
        }                                                                                  \
        float mn = dlds[((t) + 1) * 4 + kg];                                               \
        float gi = acc[0][i_s];                                                            \
        float gf = acc[1][i_s];                                                            \
        float gg = acc[2][i_s];                                                            \
        float go = acc[3][i_s];                                                            \
        c = fsigm(gf) * (c * mreg) + fsigm(gi) * ftanh(gg);                                \
        float h2 = fsigm(go) * ftanh(c);                                                   \
        h = h2;                                                                            \
        mreg = mn;                                                                         \
        hbuf[(hb) ^ 1][kg * 160 + d] = f2bf(h2 * mn);                                      \
        hring[((t) & 15) * 640 + kg * 160 + d] = f2bf(h2);                                 \
        asm volatile("s_waitcnt lgkmcnt(0)" ::: "memory");                                 \
        __builtin_amdgcn_s_barrier();                                                      \
        asm volatile("" ::: "memory");                                                     \
    }

    for (int g = 0; g < 64; g += 2) {
        {   // even group g: consume xgA, produce xgB from x2b[1] (group g+1)
            const int tb = g * 4;
            const short* x2R = &x2b[1][0];
            short* x2W = &x2b[0][0];   // at t3: stage group g+2 into slot 0
            LSTM_STEP(tb + 0, 0, 0, xgA, xgB, x2R, 0, 0, (g > 0));
            LSTM_STEP(tb + 1, 1, 1, xgA, xgB, x2R, 0, 0, 0);
            LSTM_STEP(tb + 2, 0, 2, xgA, xgB, x2R, 0, 0, 0);
            LSTM_STEP(tb + 3, 1, 3, xgA, xgB, x2R, 1, (g + 3), 0);
        }
        {   // odd group g+1: consume xgB, produce xgA from x2b[0] (group g+2)
            const int tb = (g + 1) * 4;
            const short* x2R = &x2b[0][0];
            short* x2W = &x2b[1][0];   // at t3: stage group g+3 into slot 1
            LSTM_STEP(tb + 0, 0, 0, xgB, xgA, x2R, 0, 0, 0);
            LSTM_STEP(tb + 1, 1, 1, xgB, xgA, x2R, 0, 0, 0);
            LSTM_STEP(tb + 2, 0, 2, xgB, xgA, x2R, 0, 0, 0);
            LSTM_STEP(tb + 3, 1, 3, xgB, xgA, x2R, 1, (g + 4), 0);
        }
    }
#undef LSTM_STEP
#undef X2GIDX

    // final heads for t = 248..255 (ring slots 8..15), all 8 waves, one step each
    {
        int th = 248 + w;
        const short* hr = &hring[(th & 15) * 640];
        short8 ah[4];
#pragma unroll
        for (int kk = 0; kk < 4; ++kk)
            ah[kk] = *(const short8*)&hr[aoff + kk * 32 + kg * 8];
        f32x4 aH = {biasH, biasH, biasH, biasH};
#pragma unroll
        for (int kk = 0; kk < 4; ++kk) aH = MFMA16(ah[kk], hb4[kk], aH);
        if (l15 < 9) headbuf[(th * 1024 + b0 + kg) * 12 + l15] = aH[0];
    }

    out[3 * TB_ + (b0 + kg) * 128 + d] = h;
    out[3 * TB_ + BH_ + (b0 + kg) * 128 + d] = c;
}

// ---------------- H: elementwise logprob epilogue (reads 12-float head rows) ----------------
__global__ __launch_bounds__(256) void headepi_kernel(
    const float* __restrict__ headbuf, const float* __restrict__ lstd,
    const float* __restrict__ actions, float* __restrict__ out)
{
    const int r = blockIdx.x * 256 + threadIdx.x;
    const float* hp = headbuf + (size_t)r * 12;
    float4 m0 = *(const float4*)(hp);       // [value, mean0, mean1, mean2]
    float4 m1 = *(const float4*)(hp + 4);   // [mean3..mean6]
    float4 m2 = *(const float4*)(hp + 8);   // [mean7, -, -, -]
    const float* ap = actions + (size_t)r * 8;
    float4 a0 = *(const float4*)(ap);
    float4 a1 = *(const float4*)(ap + 4);
    float mean[8] = {m0.y, m0.z, m0.w, m1.x, m1.y, m1.z, m1.w, m2.x};
    float act[8] = {a0.x, a0.y, a0.z, a0.w, a1.x, a1.y, a1.z, a1.w};
    float lp = 0.f, lj = 0.f, entS = 0.f;
#pragma unroll
    for (int ai = 0; ai < 8; ++ai) {
        float x = act[ai];
        float xc = fminf(fmaxf(x, -1.f + 1e-6f), 1.f - 1e-6f);
        float u = 0.5f * logf((1.f + xc) / (1.f - xc));
        float ls = lstd[ai];
        float z = (u - mean[ai]) * expf(-ls);
        lp += -0.5f * z * z - ls;
        lj += logf(1.f - x * x + 1e-6f);
        entS += ls;
    }
    lp -= 8.f * 0.5f * LOG2PI_F;
    entS += 8.f * (0.5f + 0.5f * LOG2PI_F);
    out[r] = lp - lj;
    out[TB_ + r] = entS + lj;
    out[2 * TB_ + r] = m0.x;
}

extern "C" void kernel_launch(void* const* d_in, const int* in_sizes, int n_in,
                              void* d_out, int out_size, void* d_ws, size_t ws_size,
                              hipStream_t stream) {
    const float* obs   = (const float*)d_in[0];
    const float* acts  = (const float*)d_in[1];
    const float* dones = (const float*)d_in[2];
    const float* h0    = (const float*)d_in[3];
    const float* c0    = (const float*)d_in[4];
    const float* w1    = (const float*)d_in[5];
    const float* b1    = (const float*)d_in[6];
    const float* w2    = (const float*)d_in[7];
    const float* b2    = (const float*)d_in[8];
    const float* wih   = (const float*)d_in[9];
    const float* whh   = (const float*)d_in[10];
    const float* bih   = (const float*)d_in[11];
    const float* bhh   = (const float*)d_in[12];
    const float* amw   = (const float*)d_in[13];
    const float* amb   = (const float*)d_in[14];
    const float* lstd  = (const float*)d_in[15];
    const float* crw   = (const float*)d_in[16];
    const float* crb   = (const float*)d_in[17];
    float* out = (float*)d_out;

    char* ws = (char*)d_ws;
    short* x2p = (short*)(ws);                       // 64 MB  [t][blk][j][dim] bf16
    float* hbf = (float*)(ws + 67108864);            // 12.6 MB [t*1024+b][12] f32
    if (ws_size < (size_t)67108864 + 12582912) return;

    hipLaunchKernelGGL(ex_kernel, dim3(512), dim3(512), 0, stream,
                       obs, b1, b2, w1, w2, x2p);
    hipLaunchKernelGGL(lstm_kernel, dim3(256), dim3(512), 0, stream,
                       x2p, whh, wih, h0, c0, bhh, bih, dones, amw, crw, amb, crb, hbf, out);
    hipLaunchKernelGGL(headepi_kernel, dim3(1024), dim3(256), 0, stream,
                       hbf, lstd, acts, out);
}